// Round 6
// baseline (183.550 us; speedup 1.0000x reference)
//
#include <hip/hip_runtime.h>
#include <hip/hip_bf16.h>
#include <stdint.h>

#define NNODES 100000
#define NEDGES 600000
#define SCAN_CHUNK 1024
#define SCAN_NB 98  // ceil(100000/1024)

typedef __attribute__((ext_vector_type(8))) short bf16x8;
typedef __attribute__((ext_vector_type(4))) float f32x4;

__device__ inline float b2f(short b) {
    union { unsigned u; float f; } v;
    v.u = ((unsigned)(unsigned short)b) << 16;
    return v.f;
}
__device__ inline short f2b(float f) {
    union { float f; unsigned u; } v;
    v.f = f;
    unsigned r = (v.u + 0x7FFFu + ((v.u >> 16) & 1u)) >> 16;
    return (short)r;
}
// LDS XOR swizzle: bank-conflict-free ds_read_b128 of row-major [row][128*2B] bf16 tiles
__device__ inline int swz(int row, int kbyte) {
    return (row * 256 + kbyte) ^ ((row & 7) << 4);
}
#define MFMA16(a, b, c) __builtin_amdgcn_mfma_f32_16x16x32_bf16(a, b, c, 0, 0, 0)

// ---------------- fused prep ----------------
// zero pos/stats; x->bf16 (+zero row); weights -> bf16 packed in per-lane MFMA
// B-fragment order: Wpk[kb][cb][lane][j]  (lane = ((k>>3)&3)*16 + (c&15), j = k&7)
__global__ __launch_bounds__(256) void k_prep(const float* __restrict__ x,
                                              const float* __restrict__ W1,
                                              const float* __restrict__ W2,
                                              const float* __restrict__ Wm1,
                                              const float* __restrict__ Wm2,
                                              short* __restrict__ xb, short* __restrict__ Wt,
                                              int* __restrict__ pos, float* __restrict__ stats) {
    int i = blockIdx.x * 256 + threadIdx.x;
    if (i < (NNODES + 1) * 16) {
        bf16x8 o = (bf16x8){0, 0, 0, 0, 0, 0, 0, 0};
        if (i < NNODES * 16) {
            const float4* p = (const float4*)(x + (size_t)i * 8);
            float4 a = p[0], b = p[1];
            o[0] = f2b(a.x); o[1] = f2b(a.y); o[2] = f2b(a.z); o[3] = f2b(a.w);
            o[4] = f2b(b.x); o[5] = f2b(b.y); o[6] = f2b(b.z); o[7] = f2b(b.w);
        }
        *(bf16x8*)(xb + (size_t)i * 8) = o;
    }
    if (i < NNODES) pos[i] = 0;
    if (i < 57344) {
        float v;
        int c, k, base, ncb;
        if (i < 16384) {
            c = i >> 7; k = i & 127; v = W1[k * 128 + c]; base = 0; ncb = 8;
        } else if (i < 32768) {
            int j = i - 16384; c = j >> 7; k = j & 127; v = W2[k * 128 + c]; base = 16384; ncb = 8;
        } else if (i < 49152) {
            int j = i - 32768; c = j >> 7; k = j & 127; v = Wm1[k * 128 + c]; base = 32768; ncb = 8;
        } else {
            int j = i - 49152; c = j >> 7; k = j & 127; v = Wm2[k * 64 + c]; base = 49152; ncb = 4;
        }
        int kb = k >> 5, hi = (k >> 3) & 3, jj = k & 7;
        int cb = c >> 4, lr = c & 15;
        int lane = hi * 16 + lr;
        int dst = base + (((kb * ncb) + cb) * 64 + lane) * 8 + jj;
        Wt[dst] = f2b(v);
    }
    if (i < 256) stats[i] = 0.0f;
}

// ---------------- CSR build ----------------

__global__ __launch_bounds__(256) void k_hist(const int* __restrict__ ei, int* __restrict__ cnt) {
    int e = blockIdx.x * 256 + threadIdx.x;
    if (e < NEDGES) atomicAdd(&cnt[ei[NEDGES + e]], 1);
}

__global__ __launch_bounds__(256) void k_scan1(const int* __restrict__ cnt, int* __restrict__ bsums) {
    __shared__ int sd[256];
    int b = blockIdx.x, t = threadIdx.x;
    int base = b * SCAN_CHUNK + t * 4;
    int s = 0;
#pragma unroll
    for (int i = 0; i < 4; ++i) {
        int idx = base + i;
        if (idx < NNODES) s += cnt[idx];
    }
    sd[t] = s;
    __syncthreads();
    for (int off = 128; off > 0; off >>= 1) {
        if (t < off) sd[t] += sd[t + off];
        __syncthreads();
    }
    if (t == 0) bsums[b] = sd[0];
}

__global__ __launch_bounds__(64) void k_scan2(int* __restrict__ bsums, int* __restrict__ rowptr) {
    if (threadIdx.x == 0 && blockIdx.x == 0) {
        int run = 0;
        for (int b = 0; b < SCAN_NB; ++b) {
            int v = bsums[b];
            bsums[b] = run;
            run += v;
        }
        rowptr[NNODES] = run;
    }
}

__global__ __launch_bounds__(256) void k_scan3(const int* __restrict__ cnt,
                                               const int* __restrict__ bsums,
                                               int* __restrict__ rowptr, int* __restrict__ pos) {
    __shared__ int sd[256];
    int b = blockIdx.x, t = threadIdx.x;
    int base = b * SCAN_CHUNK + t * 4;
    int v[4];
    int s = 0;
#pragma unroll
    for (int i = 0; i < 4; ++i) {
        int idx = base + i;
        v[i] = (idx < NNODES) ? cnt[idx] : 0;
        s += v[i];
    }
    sd[t] = s;
    __syncthreads();
    for (int off = 1; off < 256; off <<= 1) {
        int val = (t >= off) ? sd[t - off] : 0;
        __syncthreads();
        sd[t] += val;
        __syncthreads();
    }
    int run = sd[t] - s + bsums[b];
#pragma unroll
    for (int i = 0; i < 4; ++i) {
        int idx = base + i;
        if (idx < NNODES) {
            rowptr[idx] = run;
            pos[idx] = run;
            run += v[i];
        }
    }
}

__global__ __launch_bounds__(256) void k_fill(const int* __restrict__ ei, int* __restrict__ pos,
                                              int* __restrict__ elist) {
    int e = blockIdx.x * 256 + threadIdx.x;
    if (e >= NEDGES) return;
    int src = ei[e];
    int dst = ei[NEDGES + e];
    int p = atomicAdd(&pos[dst], 1);
    elist[p] = src;
}

// ---------------- gather-aggregate ----------------
__global__ __launch_bounds__(256) void k_agg(const short* __restrict__ xb,
                                             const int* __restrict__ rowptr,
                                             const int* __restrict__ elist,
                                             short* __restrict__ bufb) {
    int t = threadIdx.x;
    int w = t >> 6, lane = t & 63;
    int node = blockIdx.x * 4 + w;
    if (node >= NNODES) return;
    int beg = rowptr[node];
    int end = rowptr[node + 1];
    int deg = end - beg;
    int total = deg + 1;
    int sub = lane & 31, half = lane >> 5;
    const uint2* xr = (const uint2*)xb;

    float acc0 = 0.f, acc1 = 0.f, acc2 = 0.f, acc3 = 0.f;

    for (int base = 0; base < total; base += 64) {
        int j = base + lane;
        int ej = NNODES;  // zero row
        if (j < total) ej = (j == 0) ? node : elist[beg + j - 1];
        int cnt = min(64, total - base);
        int pairs = (cnt + 1) >> 1;
        for (int i = 0; i < pairs; i += 4) {
            int j0 = 2 * i + half;
            int r0 = __shfl(ej, j0);
            int r1 = __shfl(ej, j0 + 2);
            int r2 = __shfl(ej, j0 + 4);
            int r3 = __shfl(ej, j0 + 6);
            uint2 v0 = xr[(size_t)r0 * 32 + sub];
            uint2 v1 = xr[(size_t)r1 * 32 + sub];
            uint2 v2 = xr[(size_t)r2 * 32 + sub];
            uint2 v3 = xr[(size_t)r3 * 32 + sub];
            acc0 += b2f((short)(v0.x & 0xFFFF)) + b2f((short)(v1.x & 0xFFFF)) +
                    b2f((short)(v2.x & 0xFFFF)) + b2f((short)(v3.x & 0xFFFF));
            acc1 += b2f((short)(v0.x >> 16)) + b2f((short)(v1.x >> 16)) +
                    b2f((short)(v2.x >> 16)) + b2f((short)(v3.x >> 16));
            acc2 += b2f((short)(v0.y & 0xFFFF)) + b2f((short)(v1.y & 0xFFFF)) +
                    b2f((short)(v2.y & 0xFFFF)) + b2f((short)(v3.y & 0xFFFF));
            acc3 += b2f((short)(v0.y >> 16)) + b2f((short)(v1.y >> 16)) +
                    b2f((short)(v2.y >> 16)) + b2f((short)(v3.y >> 16));
        }
    }
    acc0 += __shfl_xor(acc0, 32);
    acc1 += __shfl_xor(acc1, 32);
    acc2 += __shfl_xor(acc2, 32);
    acc3 += __shfl_xor(acc3, 32);
    if (half == 0) {
        uint2 o;
        o.x = ((uint32_t)(unsigned short)f2b(acc1) << 16) | (uint32_t)(unsigned short)f2b(acc0);
        o.y = ((uint32_t)(unsigned short)f2b(acc3) << 16) | (uint32_t)(unsigned short)f2b(acc2);
        ((uint2*)bufb)[(size_t)node * 32 + sub] = o;
    }
}

// ---------------- stats: u = agg @ W1 (no bias; b1 cancels in BN); S,Q per col ------
__global__ __launch_bounds__(256) void k_stats(const short* __restrict__ bufb,
                                               const short* __restrict__ W1pk,
                                               float* __restrict__ stats) {
    __shared__ float Sred[2][4][128];
    int t = threadIdx.x, w = t >> 6, l = t & 63;
    int r0 = blockIdx.x * 128;
    int row0 = (w & 1) * 64, col0 = (w >> 1) * 64;

    f32x4 acc[4][4];
#pragma unroll
    for (int r = 0; r < 4; ++r)
#pragma unroll
        for (int c = 0; c < 4; ++c) acc[r][c] = (f32x4){0.f, 0.f, 0.f, 0.f};

#pragma unroll
    for (int kb = 0; kb < 4; ++kb) {
        bf16x8 af[4], bw[4];
#pragma unroll
        for (int r = 0; r < 4; ++r)
            af[r] = *(const bf16x8*)(bufb + (size_t)(r0 + row0 + r * 16 + (l & 15)) * 128 +
                                     kb * 32 + (l >> 4) * 8);
#pragma unroll
        for (int c = 0; c < 4; ++c)
            bw[c] = *(const bf16x8*)(W1pk + ((kb * 8 + (w >> 1) * 4 + c) * 64 + l) * 8);
#pragma unroll
        for (int r = 0; r < 4; ++r)
#pragma unroll
            for (int c = 0; c < 4; ++c) acc[r][c] = MFMA16(af[r], bw[c], acc[r][c]);
    }

    float s[4], q[4];
#pragma unroll
    for (int c = 0; c < 4; ++c) { s[c] = 0.f; q[c] = 0.f; }
#pragma unroll
    for (int c = 0; c < 4; ++c)
#pragma unroll
        for (int r = 0; r < 4; ++r)
#pragma unroll
            for (int rr = 0; rr < 4; ++rr) {
                int grow = r0 + row0 + r * 16 + (l >> 4) * 4 + rr;
                if (grow < NNODES) {
                    float v = acc[r][c][rr];
                    s[c] += v;
                    q[c] += v * v;
                }
            }
#pragma unroll
    for (int c = 0; c < 4; ++c) {
        s[c] += __shfl_xor(s[c], 16); s[c] += __shfl_xor(s[c], 32);
        q[c] += __shfl_xor(q[c], 16); q[c] += __shfl_xor(q[c], 32);
    }
    if (l < 16) {
#pragma unroll
        for (int c = 0; c < 4; ++c) {
            Sred[0][w][col0 + c * 16 + l] = s[c];
            Sred[1][w][col0 + c * 16 + l] = q[c];
        }
    }
    __syncthreads();
    if (t < 128) {
        int wb = (t < 64) ? 0 : 2;
        atomicAdd(stats + t, Sred[0][wb][t] + Sred[0][wb + 1][t]);
        atomicAdd(stats + 128 + t, Sred[1][wb][t] + Sred[1][wb + 1][t]);
    }
}

// ---------------- wave-independent fused MLP: one wave per 64 rows, no barriers -----
__global__ __launch_bounds__(64) void k_mlp(const short* __restrict__ bufb,
                                            const float* __restrict__ stats,
                                            const float* __restrict__ gamma,
                                            const float* __restrict__ beta,
                                            const short* __restrict__ Wt,
                                            const float* __restrict__ b2,
                                            const float* __restrict__ bm1,
                                            const float* __restrict__ bm2,
                                            float* __restrict__ out) {
    __shared__ __align__(16) short act[64 * 128];  // 16KB, wave-private
    __shared__ float scale[128], shift[128], b2s[128], bm1s[128], bm2s[64];

    int l = threadIdx.x;
    int lr = l & 15, hi = l >> 4;
    size_t r0w = (size_t)blockIdx.x * 64;
    const short* W1pk = Wt;
    const short* W2pk = Wt + 16384;
    const short* Wm1pk = Wt + 32768;
    const short* Wm2pk = Wt + 49152;

#pragma unroll
    for (int i = 0; i < 2; ++i) {
        int idx = l + i * 64;
        float mean = stats[idx] * (1.0f / NNODES);
        float var = stats[128 + idx] * (1.0f / NNODES) - mean * mean;
        var = fmaxf(var, 0.0f);
        float inv = rsqrtf(var + 1e-5f);
        float sc = gamma[idx] * inv;
        scale[idx] = sc;
        shift[idx] = beta[idx] - mean * sc;  // b1 cancels in batch-stats BN
        b2s[idx] = b2[idx];
        bm1s[idx] = bm1[idx];
    }
    bm2s[l] = bm2[l];
    __syncthreads();  // single wave: cheap; orders LDS init vs use

    bf16x8 af[4][4];
    f32x4 acc[4][4];

    // ---- G1: A from global (bufb), BN+ReLU -> act ----
#pragma unroll
    for (int kb = 0; kb < 4; ++kb)
#pragma unroll
        for (int r = 0; r < 4; ++r)
            af[kb][r] = *(const bf16x8*)(bufb + (r0w + r * 16 + lr) * 128 + kb * 32 + hi * 8);

#pragma unroll
    for (int p = 0; p < 2; ++p) {
#pragma unroll
        for (int r = 0; r < 4; ++r)
#pragma unroll
            for (int c = 0; c < 4; ++c) acc[r][c] = (f32x4){0.f, 0.f, 0.f, 0.f};
        __builtin_amdgcn_s_setprio(1);
#pragma unroll
        for (int kb = 0; kb < 4; ++kb) {
            bf16x8 bw[4];
#pragma unroll
            for (int c = 0; c < 4; ++c)
                bw[c] = *(const bf16x8*)(W1pk + ((kb * 8 + p * 4 + c) * 64 + l) * 8);
#pragma unroll
            for (int r = 0; r < 4; ++r)
#pragma unroll
                for (int c = 0; c < 4; ++c) acc[r][c] = MFMA16(af[kb][r], bw[c], acc[r][c]);
        }
        __builtin_amdgcn_s_setprio(0);
#pragma unroll
        for (int c = 0; c < 4; ++c) {
            int col = p * 64 + c * 16 + lr;
            float sc_ = scale[col], sh_ = shift[col];
#pragma unroll
            for (int r = 0; r < 4; ++r)
#pragma unroll
                for (int rr = 0; rr < 4; ++rr) {
                    int row = r * 16 + hi * 4 + rr;
                    *(short*)((char*)act + swz(row, col * 2)) =
                        f2b(fmaxf(acc[r][c][rr] * sc_ + sh_, 0.f));
                }
        }
    }

    // ---- G2: A from act (regs first, then overwrite act), +b2, ReLU ----
#pragma unroll
    for (int kb = 0; kb < 4; ++kb)
#pragma unroll
        for (int r = 0; r < 4; ++r)
            af[kb][r] = *(const bf16x8*)((char*)act + swz(r * 16 + lr, kb * 64 + hi * 16));

#pragma unroll
    for (int p = 0; p < 2; ++p) {
#pragma unroll
        for (int r = 0; r < 4; ++r)
#pragma unroll
            for (int c = 0; c < 4; ++c) acc[r][c] = (f32x4){0.f, 0.f, 0.f, 0.f};
        __builtin_amdgcn_s_setprio(1);
#pragma unroll
        for (int kb = 0; kb < 4; ++kb) {
            bf16x8 bw[4];
#pragma unroll
            for (int c = 0; c < 4; ++c)
                bw[c] = *(const bf16x8*)(W2pk + ((kb * 8 + p * 4 + c) * 64 + l) * 8);
#pragma unroll
            for (int r = 0; r < 4; ++r)
#pragma unroll
                for (int c = 0; c < 4; ++c) acc[r][c] = MFMA16(af[kb][r], bw[c], acc[r][c]);
        }
        __builtin_amdgcn_s_setprio(0);
#pragma unroll
        for (int c = 0; c < 4; ++c) {
            int col = p * 64 + c * 16 + lr;
            float bias = b2s[col];
#pragma unroll
            for (int r = 0; r < 4; ++r)
#pragma unroll
                for (int rr = 0; rr < 4; ++rr) {
                    int row = r * 16 + hi * 4 + rr;
                    *(short*)((char*)act + swz(row, col * 2)) =
                        f2b(fmaxf(acc[r][c][rr] + bias, 0.f));
                }
        }
    }

    // ---- G3: same pattern with Wm1, +bm1, ReLU ----
#pragma unroll
    for (int kb = 0; kb < 4; ++kb)
#pragma unroll
        for (int r = 0; r < 4; ++r)
            af[kb][r] = *(const bf16x8*)((char*)act + swz(r * 16 + lr, kb * 64 + hi * 16));

#pragma unroll
    for (int p = 0; p < 2; ++p) {
#pragma unroll
        for (int r = 0; r < 4; ++r)
#pragma unroll
            for (int c = 0; c < 4; ++c) acc[r][c] = (f32x4){0.f, 0.f, 0.f, 0.f};
        __builtin_amdgcn_s_setprio(1);
#pragma unroll
        for (int kb = 0; kb < 4; ++kb) {
            bf16x8 bw[4];
#pragma unroll
            for (int c = 0; c < 4; ++c)
                bw[c] = *(const bf16x8*)(Wm1pk + ((kb * 8 + p * 4 + c) * 64 + l) * 8);
#pragma unroll
            for (int r = 0; r < 4; ++r)
#pragma unroll
                for (int c = 0; c < 4; ++c) acc[r][c] = MFMA16(af[kb][r], bw[c], acc[r][c]);
        }
        __builtin_amdgcn_s_setprio(0);
#pragma unroll
        for (int c = 0; c < 4; ++c) {
            int col = p * 64 + c * 16 + lr;
            float bias = bm1s[col];
#pragma unroll
            for (int r = 0; r < 4; ++r)
#pragma unroll
                for (int rr = 0; rr < 4; ++rr) {
                    int row = r * 16 + hi * 4 + rr;
                    *(short*)((char*)act + swz(row, col * 2)) =
                        f2b(fmaxf(acc[r][c][rr] + bias, 0.f));
                }
        }
    }

    // ---- G4: [64 x 64] output, +bm2 -> out ----
#pragma unroll
    for (int kb = 0; kb < 4; ++kb)
#pragma unroll
        for (int r = 0; r < 4; ++r)
            af[kb][r] = *(const bf16x8*)((char*)act + swz(r * 16 + lr, kb * 64 + hi * 16));

#pragma unroll
    for (int r = 0; r < 4; ++r)
#pragma unroll
        for (int c = 0; c < 4; ++c) acc[r][c] = (f32x4){0.f, 0.f, 0.f, 0.f};
    __builtin_amdgcn_s_setprio(1);
#pragma unroll
    for (int kb = 0; kb < 4; ++kb) {
        bf16x8 bw[4];
#pragma unroll
        for (int c = 0; c < 4; ++c)
            bw[c] = *(const bf16x8*)(Wm2pk + ((kb * 4 + c) * 64 + l) * 8);
#pragma unroll
        for (int r = 0; r < 4; ++r)
#pragma unroll
            for (int c = 0; c < 4; ++c) acc[r][c] = MFMA16(af[kb][r], bw[c], acc[r][c]);
    }
    __builtin_amdgcn_s_setprio(0);
#pragma unroll
    for (int c = 0; c < 4; ++c) {
        float bias = bm2s[c * 16 + lr];
#pragma unroll
        for (int r = 0; r < 4; ++r)
#pragma unroll
            for (int rr = 0; rr < 4; ++rr) {
                size_t grow = r0w + r * 16 + hi * 4 + rr;
                if (grow < NNODES)
                    out[grow * 64 + c * 16 + lr] = acc[r][c][rr] + bias;
            }
    }
}

// ---------------- launch ----------------
extern "C" void kernel_launch(void* const* d_in, const int* in_sizes, int n_in,
                              void* d_out, int out_size, void* d_ws, size_t ws_size,
                              hipStream_t stream) {
    const float* x     = (const float*)d_in[0];
    const int*   ei    = (const int*)d_in[1];
    const float* W1    = (const float*)d_in[2];
    const float* gamma = (const float*)d_in[4];
    const float* beta  = (const float*)d_in[5];
    const float* W2    = (const float*)d_in[6];
    const float* b2    = (const float*)d_in[7];
    const float* Wm1   = (const float*)d_in[8];
    const float* bm1   = (const float*)d_in[9];
    const float* Wm2   = (const float*)d_in[10];
    const float* bm2   = (const float*)d_in[11];
    float* out = (float*)d_out;

    char* ws = (char*)d_ws;
    short* xb    = (short*)ws;                           // (N+1)*128 bf16 (last row zeros)
    short* bufb  = xb + (size_t)(NNODES + 1) * 128;      // (N+128)*128 bf16 (tail padding)
    short* Wt    = bufb + (size_t)(NNODES + 128) * 128;  // 57344 bf16 packed fragments
    float* stats = (float*)(Wt + 57344);                 // 256 f32
    int* rowptr  = (int*)(stats + 256);                  // N+1
    int* pos     = rowptr + (NNODES + 1);                // N
    int* elist   = pos + NNODES;                         // E
    int* bsums   = elist + NEDGES;                       // 128

    int gE = (NEDGES + 255) / 256;
    int gPrep = ((NNODES + 1) * 16 + 255) / 256;

    k_prep<<<gPrep, 256, 0, stream>>>(x, W1, W2, Wm1, Wm2, xb, Wt, pos, stats);
    k_hist<<<gE, 256, 0, stream>>>(ei, pos);
    k_scan1<<<SCAN_NB, 256, 0, stream>>>(pos, bsums);
    k_scan2<<<1, 64, 0, stream>>>(bsums, rowptr);
    k_scan3<<<SCAN_NB, 256, 0, stream>>>(pos, bsums, rowptr, pos);
    k_fill<<<gE, 256, 0, stream>>>(ei, pos, elist);
    k_agg<<<(NNODES + 3) / 4, 256, 0, stream>>>(xb, rowptr, elist, bufb);

    int nblkS = (NNODES + 127) / 128;
    k_stats<<<nblkS, 256, 0, stream>>>(bufb, Wt, stats);
    int nblkM = (NNODES + 63) / 64;
    k_mlp<<<nblkM, 64, 0, stream>>>(bufb, stats, gamma, beta, Wt, b2, bm1, bm2, out);
}